// Round 16
// baseline (214.159 us; speedup 1.0000x reference)
//
#include <hip/hip_runtime.h>

typedef unsigned short u16;
typedef _Float16 f16;

#define CIN   64
#define HH    128
#define WW    128
#define NPIX  16384   /* HH*WW */
#define HID   256
#define MTOT  512     /* coef(256) + freq(256) stacked */
#define KTOT  576     /* 64 ch * 9 taps */
#define NB    4
#define WELEM 294912  /* MTOT*KTOT */
#define XROW  130     /* padded input grid row */
#define XROWS 16900   /* 130*130 rows per batch */
#define RECB  768     /* YT record: 256 int8 coef + 256 int16 freq */

/* index-path constants: must bit-match the f32 trace of the reference */
#define SHM  ((float)(-0.0078125 + 1e-6))
#define SHP  ((float)( 0.0078125 + 1e-6))
#define CLO  ((float)(-1.0 + 1e-6))
#define CHI  ((float)( 1.0 - 1e-6))
#define PIF  3.14159265358979323846f

#define QSCL   1024.0f         /* int16 fixed-point scale (freq) */
#define QISCL  (1.0f / 1024.0f)
#define Q8SCL  16.0f           /* int8 fixed-point scale (coef)  */
#define Q8ISCL 0.0625f

using f32x4 = __attribute__((ext_vector_type(4))) float;
using f16x8 = __attribute__((ext_vector_type(8))) _Float16;

/* ---- async global->LDS DMA (dest = wave base + lane*size).
   ONLY widths 4 and 16 are HW-validated (m03/m97); width 12 corrupts
   LDS (R15: lane stride is 16 for dwordx3 -> slot overflow -> NaN). ---- */
typedef __attribute__((address_space(1))) const void gas_void;
typedef __attribute__((address_space(3))) void las_void;
__device__ __forceinline__ void gload16(const void* g, void* l) {
  __builtin_amdgcn_global_load_lds((gas_void*)g, (las_void*)l, 16, 0, 0);
}
__device__ __forceinline__ void gload4(const void* g, void* l) {
  __builtin_amdgcn_global_load_lds((gas_void*)g, (las_void*)l, 4, 0, 0);
}

__device__ __forceinline__ unsigned packq(float a, float b) {  /* int16 x2 */
  float fa = fminf(fmaxf(a * QSCL, -32767.f), 32767.f);
  float fb = fminf(fmaxf(b * QSCL, -32767.f), 32767.f);
  int ia = (int)rintf(fa), ib = (int)rintf(fb);
  return ((unsigned)(unsigned short)(short)ia) | (((unsigned)(unsigned short)(short)ib) << 16);
}
__device__ __forceinline__ unsigned pack8(float a, float b, float c, float d) { /* int8 x4 */
  int ia = (int)rintf(fminf(fmaxf(a * Q8SCL, -127.f), 127.f));
  int ib = (int)rintf(fminf(fmaxf(b * Q8SCL, -127.f), 127.f));
  int ic = (int)rintf(fminf(fmaxf(c * Q8SCL, -127.f), 127.f));
  int id = (int)rintf(fminf(fmaxf(d * Q8SCL, -127.f), 127.f));
  return (ia & 255) | ((ib & 255) << 8) | ((ic & 255) << 16) | ((id & 255) << 24);
}

/* =====================================================================
 * Kernel 1: repack conv weights -> fp16 for DIRECT global->register
 * fragment loads (layout validated R10-R14).
 * ===================================================================== */
__global__ __launch_bounds__(256) void lte_prep_w(
    const float* __restrict__ cw, const float* __restrict__ fw,
    f16* __restrict__ Awp) {
  int id = blockIdx.x * 256 + threadIdx.x;
  if (id >= WELEM) return;
  int e  = id & 7;
  int l  = (id >> 3) & 63;
  int mi = (id >> 9) & 3;
  int r  = id >> 11;
  int ks = r & 1;
  int r2 = r >> 1;
  int s  = r2 % 9;
  int q  = r2 / 9;
  int wr = q & 1;
  int mt = q >> 1;
  int m  = mt * 128 + wr * 64 + mi * 16 + (l & 15);
  int ch = (ks * 4 + (l >> 4)) * 8 + e;
  const float* src = (m < HID) ? cw : fw;
  Awp[id] = (f16)src[(m & 255) * KTOT + ch * 9 + s];
}

/* =====================================================================
 * Kernel 1b: input NCHW f32 -> zero-guard-padded pixel-major fp16
 * xp[b][130][130][64], 16B chunks XOR-permuted by (padded_col & 7).
 * ===================================================================== */
__global__ __launch_bounds__(256) void lte_prep_x(
    const float* __restrict__ inp, f16* __restrict__ xp) {
  int id = blockIdx.x * 256 + threadIdx.x;   /* padded row id, NB*16900 */
  if (id >= NB * XROWS) return;
  int b  = id / XROWS;
  int rr = id - b * XROWS;
  int yy = rr / XROW;
  int pc = rr - yy * XROW;      /* padded col 0..129 */
  int x  = pc - 1;
  int y  = yy - 1;
  f16* op = xp + (size_t)id * 64;
  if ((unsigned)y < 128u && (unsigned)x < 128u) {
    const float* ip = inp + (size_t)b * CIN * NPIX + y * WW + x;
    const int p7 = pc & 7;
#pragma unroll
    for (int q = 0; q < 8; ++q) {
      f16x8 v;
#pragma unroll
      for (int k = 0; k < 8; ++k) v[k] = (f16)ip[(((q ^ p7) << 3) + k) * NPIX];
      *(f16x8*)(op + q * 8) = v;
    }
  } else {
    f16x8 z = {};
#pragma unroll
    for (int q = 0; q < 8; ++q) *(f16x8*)(op + q * 8) = z;
  }
}

/* =====================================================================
 * Kernel 2: implicit-im2col GEMM (validated R10-R14). UNCHANGED.
 * ===================================================================== */
__global__ __launch_bounds__(256, 3) void lte_conv_gemm(
    const f16* __restrict__ xp, const f16* __restrict__ Awp,
    const float* __restrict__ coef_b, const float* __restrict__ freq_b,
    char* __restrict__ YT) {
  __shared__ f16 Bs[3 * 136 * 64];    /* 52,224 B; reused by epilogue */

  const int t  = threadIdx.x;
  const int bx = blockIdx.x;
  const int mt = blockIdx.y;
  const int bb = blockIdx.z;
  const int l  = t & 63;
  const int w  = t >> 6;
  const int wr = __builtin_amdgcn_readfirstlane(w >> 1);
  const int wc = __builtin_amdgcn_readfirstlane(w & 1);
  const int lm = l & 15;

  f32x4 acc[4][4] = {};

  const f16* xb = xp + (size_t)bb * XROWS * 64;
  const f16* Aw = Awp + (size_t)((mt * 2 + wr) * 9) * 4096 + l * 8;

  for (int c = w; c < 51; c += 4) {
    const int rr = c / 17, cc = c - rr * 17;
    gload16(xb + (size_t)((bx + rr) * XROW + cc * 8) * 64 + l * 8,
            Bs + (rr * 136 + cc * 8) * 64);
  }

  f16x8 afb[2][4];
#define LOAD_AF(buf_, h_)                                                    \
  {                                                                          \
    const f16* ap_ = Aw + ((h_) >> 1) * 4096 + ((h_) & 1) * 2048;            \
    afb[buf_][0] = *(const f16x8*)(ap_);                                     \
    afb[buf_][1] = *(const f16x8*)(ap_ + 512);                               \
    afb[buf_][2] = *(const f16x8*)(ap_ + 1024);                              \
    afb[buf_][3] = *(const f16x8*)(ap_ + 1536);                              \
  }

  LOAD_AF(0, 0)
  asm volatile("s_waitcnt vmcnt(0)" ::: "memory");
  __builtin_amdgcn_s_barrier();

#pragma unroll
  for (int h = 0; h < 18; ++h) {
    const int s  = h >> 1;
    const int ks = h & 1;
    if (h < 17) LOAD_AF((h + 1) & 1, h + 1)
    const int ky = s / 3, kx = s - 3 * (s / 3);
    const int jl = ks * 4 + (l >> 4);
    f16x8 bg[4];
#pragma unroll
    for (int ni = 0; ni < 4; ++ni) {
      const int xc = wc * 64 + ni * 16 + lm + kx;
      bg[ni] = *(const f16x8*)&Bs[(ky * 136 + xc) * 64 + ((jl ^ (xc & 7)) << 3)];
    }
#pragma unroll
    for (int mi = 0; mi < 4; ++mi)
#pragma unroll
      for (int ni = 0; ni < 4; ++ni)
        acc[mi][ni] = __builtin_amdgcn_mfma_f32_16x16x32_f16(afb[h & 1][mi], bg[ni], acc[mi][ni], 0, 0, 0);
  }

  __syncthreads();
  const float* bias = (mt < 2) ? (coef_b + mt * 128) : (freq_b + (mt - 2) * 128);
  const int rj = (l >> 4) * 4;
  if (mt < 2) {
    char* lt8 = (char*)Bs;               /* [128][144] */
#pragma unroll
    for (int mi = 0; mi < 4; ++mi) {
      const int bm = wr * 64 + mi * 16 + rj;
      const float b0 = bias[bm], b1 = bias[bm + 1], b2 = bias[bm + 2], b3 = bias[bm + 3];
#pragma unroll
      for (int ni = 0; ni < 4; ++ni) {
        const int p = wc * 64 + ni * 16 + lm;
        f32x4 v = acc[mi][ni];
        *(unsigned*)&lt8[p * 144 + bm] = pack8(v[0] + b0, v[1] + b1, v[2] + b2, v[3] + b3);
      }
    }
    __syncthreads();
    char* yb8 = YT + (size_t)(bb * NPIX + bx * 128) * RECB + mt * 128;
#pragma unroll
    for (int it = 0; it < 4; ++it) {
      const int p = it * 32 + (t >> 3);
      const int off = (t & 7) * 16;
      uint4 v = *(const uint4*)&lt8[p * 144 + off];
      *(uint4*)&yb8[(size_t)p * RECB + off] = v;
    }
  } else {
    short* lt = (short*)Bs;              /* [128][138] */
#pragma unroll
    for (int mi = 0; mi < 4; ++mi) {
      const int bm = wr * 64 + mi * 16 + rj;
      const float b0 = bias[bm], b1 = bias[bm + 1], b2 = bias[bm + 2], b3 = bias[bm + 3];
#pragma unroll
      for (int ni = 0; ni < 4; ++ni) {
        const int p = wc * 64 + ni * 16 + lm;
        f32x4 v = acc[mi][ni];
        uint2 q2; q2.x = packq(v[0] + b0, v[1] + b1); q2.y = packq(v[2] + b2, v[3] + b3);
        *(uint2*)&lt[p * 138 + bm] = q2;
      }
    }
    __syncthreads();
    short* yb = (short*)(YT + (size_t)(bb * NPIX + bx * 128) * RECB + 256) + (mt - 2) * 128;
    const int lp = l >> 5;
    const int c4 = (l & 31) * 4;
#pragma unroll
    for (int it = 0; it < 16; ++it) {
      const int p = it * 8 + w * 2 + lp;
      uint2 v = *(const uint2*)&lt[p * 138 + c4];
      *(uint2*)&yb[(size_t)p * (RECB / 2) + c4] = v;
    }
  }
}

/* =====================================================================
 * Kernel 3: 4-corner nearest sample + sin/cos modulation.
 * Async LDS-gather pipeline (R15 structure), DMA re-expressed in the
 * VALIDATED width-4 mode: each 768B record = 3 calls x (64 lanes x 4B),
 * compact layout, zero VGPR staging cost. Quads of 4 queries (16 recs)
 * double-buffered; phase-A math overlaps DMA; raw barriers hardened
 * with lgkmcnt waits + sched_barrier (rule #18 / m152).
 * Index path bit-exact — unchanged math.
 * ===================================================================== */
__global__ __launch_bounds__(128) void lte_sample(
    const char* __restrict__ YT, const float* __restrict__ coord,
    const float* __restrict__ cell, const float* __restrict__ phase_w,
    float* __restrict__ out) {
  __shared__ float lout[256 * 17];          /* 17,408 B */
  __shared__ char  rbuf[2][16 * RECB];      /* 2 x 12,288 B */
  const int j     = threadIdx.x;          /* 0..127 */
  const int wv    = j >> 6;               /* wave 0/1 */
  const int l     = j & 63;               /* lane */
  const int q0    = blockIdx.x * 16;      /* global over B*Q */
  const int b     = q0 >> 14;
  const int q0loc = q0 & (NPIX - 1);
  const float pw0 = phase_w[2 * j], pw1 = phase_w[2 * j + 1];
  const char* Yb = YT + (size_t)b * NPIX * RECB;

  /* two-quad live state; all indices static after full unroll */
  float ph[2][4], tot[2][4], a3[2][4];
  float rel0[2][4][4], rel1[2][4][4];
  int   off[2][4][4];

  /* phase A for quad qn -> state set (qn&1). Bit-exact index path. */
#define PHASE_A(qn_)                                                         \
  {                                                                          \
    const int S_ = (qn_) & 1;                                                \
    _Pragma("unroll")                                                        \
    for (int qi = 0; qi < 4; ++qi) {                                         \
      const int qg = q0 + (qn_) * 4 + qi;                                    \
      const float c0 = coord[2 * qg], c1 = coord[2 * qg + 1];                \
      const float ce0 = cell[2 * qg], ce1 = cell[2 * qg + 1];                \
      ph[S_][qi] = (ce0 * 128.0f) * pw0 + (ce1 * 128.0f) * pw1;              \
      tot[S_][qi] = 0.f;                                                     \
      _Pragma("unroll")                                                      \
      for (int ci = 0; ci < 4; ++ci) {                                       \
        const float s0 = (ci & 2) ? SHP : SHM;                               \
        const float s1 = (ci & 1) ? SHP : SHM;                               \
        float cx = fminf(fmaxf(c0 + s0, CLO), CHI);                          \
        float cy = fminf(fmaxf(c1 + s1, CLO), CHI);                          \
        float ty = ((cx + 1.0f) * 128.0f - 1.0f) * 0.5f;                     \
        float tx = ((cy + 1.0f) * 128.0f - 1.0f) * 0.5f;                     \
        float fy = fminf(fmaxf(rintf(ty), 0.f), 127.f);                      \
        float fx = fminf(fmaxf(rintf(tx), 0.f), 127.f);                      \
        int iy = (int)fy, ix = (int)fx;                                      \
        float qcy = -1.0f + (2.0f * fy + 1.0f) * (1.0f / 128.0f);            \
        float qcx = -1.0f + (2.0f * fx + 1.0f) * (1.0f / 128.0f);            \
        rel0[S_][qi][ci] = (c0 - qcy) * 128.0f;                              \
        rel1[S_][qi][ci] = (c1 - qcx) * 128.0f;                              \
        float ar = fabsf(rel0[S_][qi][ci] * rel1[S_][qi][ci]);               \
        tot[S_][qi] += ar + 1e-9f;                                           \
        if (ci == 3) a3[S_][qi] = ar;                                        \
        off[S_][qi][ci] = (iy * 128 + ix) * RECB;                            \
      }                                                                      \
    }                                                                        \
  }

  /* stage quad qn: 8 records/wave, 3 width-4 DMA calls each (256B/call) */
#define STAGE_Q(qn_)                                                         \
  {                                                                          \
    const int S_ = (qn_) & 1;                                                \
    _Pragma("unroll")                                                        \
    for (int i = 0; i < 8; ++i) {                                            \
      const int r_ = wv * 8 + i;                                             \
      const char* gb_ = Yb + off[S_][r_ >> 2][r_ & 3];                       \
      char* lb_ = rbuf[S_] + r_ * RECB;                                      \
      gload4(gb_ + l * 4,       lb_);                                        \
      gload4(gb_ + 256 + l * 4, lb_ + 256);                                  \
      gload4(gb_ + 512 + l * 4, lb_ + 512);                                  \
    }                                                                        \
  }

  PHASE_A(0)
  STAGE_Q(0)

#pragma unroll
  for (int qq = 0; qq < 4; ++qq) {
    const int S = qq & 1;
    if (qq < 3) PHASE_A(qq + 1)                 /* VALU under DMA latency */
    asm volatile("s_waitcnt vmcnt(0)" ::: "memory");
    __builtin_amdgcn_s_barrier();
    __builtin_amdgcn_sched_barrier(0);
    if (qq < 3) STAGE_Q(qq + 1)                 /* issue-early next quad */
    /* ---- phase C: consume quad qq from LDS ---- */
#pragma unroll
    for (int qi = 0; qi < 4; ++qi) {
      float accC = 0.f, accS = 0.f;
#pragma unroll
      for (int ci = 0; ci < 4; ++ci) {
        const char* rp = rbuf[S] + (qi * 4 + ci) * RECB;
        float coefA = (float)(*(const signed char*)(rp + j)) * Q8ISCL;
        float coefB = (float)(*(const signed char*)(rp + 128 + j)) * Q8ISCL;
        int u = *(const int*)(rp + 256 + 4 * j);
        float f0 = (float)((short)(u & 0xFFFF)) * QISCL;
        float f1 = (float)((short)(u >> 16)) * QISCL;
        float f = f0 * rel0[S][qi][ci] + f1 * rel1[S][qi][ci] + ph[S][qi];
        float ang = PIF * f;
        accC += coefA * __cosf(ang);
        accS += coefB * __sinf(ang);
      }
      const float wgt = a3[S][qi] / tot[S][qi];
      lout[j * 17 + qq * 4 + qi]         = accC * wgt;
      lout[(j + 128) * 17 + qq * 4 + qi] = accS * wgt;
    }
    /* done reading rbuf[S]: drain own LDS ops, then signal */
    asm volatile("s_waitcnt lgkmcnt(0)" ::: "memory");
    __builtin_amdgcn_s_barrier();
    __builtin_amdgcn_sched_barrier(0);
  }
  __syncthreads();
#pragma unroll
  for (int pass = 0; pass < 8; ++pass) {
    int c  = pass * 32 + (j >> 2);
    int qf = (j & 3) * 4;
    float4 v;
    v.x = lout[c * 17 + qf];     v.y = lout[c * 17 + qf + 1];
    v.z = lout[c * 17 + qf + 2]; v.w = lout[c * 17 + qf + 3];
    *(float4*)(out + (((size_t)(b * 256 + c)) << 14) + q0loc + qf) = v;
  }
}

extern "C" void kernel_launch(void* const* d_in, const int* in_sizes, int n_in,
                              void* d_out, int out_size, void* d_ws, size_t ws_size,
                              hipStream_t stream) {
  const float* inp     = (const float*)d_in[0];
  const float* coord   = (const float*)d_in[1];
  const float* cell    = (const float*)d_in[2];
  const float* coef_w  = (const float*)d_in[3];
  const float* coef_b  = (const float*)d_in[4];
  const float* freq_w  = (const float*)d_in[5];
  const float* freq_b  = (const float*)d_in[6];
  const float* phase_w = (const float*)d_in[7];
  float* out = (float*)d_out;

  /* ws: Awp fp16 (0.59MB) | xp_pad fp16 (8.65MB + slack) | YT 768B-rec (50.3MB) */
  f16* Awp = (f16*)d_ws;
  f16* xp  = (f16*)((char*)d_ws + (size_t)WELEM * 2);
  char* YT = (char*)d_ws + (size_t)WELEM * 2 + ((size_t)NB * XROWS + 8) * 64 * 2;

  lte_prep_w<<<dim3(1152), dim3(256), 0, stream>>>(coef_w, freq_w, Awp);
  lte_prep_x<<<dim3((NB * XROWS + 255) / 256), dim3(256), 0, stream>>>(inp, xp);
  lte_conv_gemm<<<dim3(128, 4, 4), dim3(256), 0, stream>>>(xp, Awp, coef_b, freq_b, YT);
  lte_sample<<<dim3(4096), dim3(128), 0, stream>>>(YT, coord, cell, phase_w, out);
}

// Round 17
// 118.882 us; speedup vs baseline: 1.8014x; 1.8014x over previous
//
#include <hip/hip_runtime.h>

typedef unsigned short u16;
typedef _Float16 f16;

#define CIN   64
#define HH    128
#define WW    128
#define NPIX  16384   /* HH*WW */
#define HID   256
#define MTOT  512     /* coef(256) + freq(256) stacked */
#define KTOT  576     /* 64 ch * 9 taps */
#define NB    4
#define WELEM 294912  /* MTOT*KTOT */
#define XROW  130     /* padded input grid row */
#define XROWS 16900   /* 130*130 rows per batch */
#define RECB  768     /* YT record: 256 int8 coef + 256 int16 freq */

/* index-path constants: must bit-match the f32 trace of the reference */
#define SHM  ((float)(-0.0078125 + 1e-6))
#define SHP  ((float)( 0.0078125 + 1e-6))
#define CLO  ((float)(-1.0 + 1e-6))
#define CHI  ((float)( 1.0 - 1e-6))
#define PIF  3.14159265358979323846f

#define QSCL   1024.0f         /* int16 fixed-point scale (freq) */
#define QISCL  (1.0f / 1024.0f)
#define Q8SCL  16.0f           /* int8 fixed-point scale (coef)  */
#define Q8ISCL 0.0625f

using f32x4 = __attribute__((ext_vector_type(4))) float;
using f16x8 = __attribute__((ext_vector_type(8))) _Float16;

/* ---- async global->LDS DMA (dest = wave base + lane*16) ---- */
typedef __attribute__((address_space(1))) const void gas_void;
typedef __attribute__((address_space(3))) void las_void;
__device__ __forceinline__ void gload16(const void* g, void* l) {
  __builtin_amdgcn_global_load_lds((gas_void*)g, (las_void*)l, 16, 0, 0);
}

__device__ __forceinline__ unsigned packq(float a, float b) {  /* int16 x2 */
  float fa = fminf(fmaxf(a * QSCL, -32767.f), 32767.f);
  float fb = fminf(fmaxf(b * QSCL, -32767.f), 32767.f);
  int ia = (int)rintf(fa), ib = (int)rintf(fb);
  return ((unsigned)(unsigned short)(short)ia) | (((unsigned)(unsigned short)(short)ib) << 16);
}
__device__ __forceinline__ unsigned pack8(float a, float b, float c, float d) { /* int8 x4 */
  int ia = (int)rintf(fminf(fmaxf(a * Q8SCL, -127.f), 127.f));
  int ib = (int)rintf(fminf(fmaxf(b * Q8SCL, -127.f), 127.f));
  int ic = (int)rintf(fminf(fmaxf(c * Q8SCL, -127.f), 127.f));
  int id = (int)rintf(fminf(fmaxf(d * Q8SCL, -127.f), 127.f));
  return (ia & 255) | ((ib & 255) << 8) | ((ic & 255) << 16) | ((id & 255) << 24);
}

/* =====================================================================
 * Kernel 1: repack conv weights -> fp16 for DIRECT global->register
 * fragment loads (layout validated R10-R14).
 * ===================================================================== */
__global__ __launch_bounds__(256) void lte_prep_w(
    const float* __restrict__ cw, const float* __restrict__ fw,
    f16* __restrict__ Awp) {
  int id = blockIdx.x * 256 + threadIdx.x;
  if (id >= WELEM) return;
  int e  = id & 7;
  int l  = (id >> 3) & 63;
  int mi = (id >> 9) & 3;
  int r  = id >> 11;
  int ks = r & 1;
  int r2 = r >> 1;
  int s  = r2 % 9;
  int q  = r2 / 9;
  int wr = q & 1;
  int mt = q >> 1;
  int m  = mt * 128 + wr * 64 + mi * 16 + (l & 15);
  int ch = (ks * 4 + (l >> 4)) * 8 + e;
  const float* src = (m < HID) ? cw : fw;
  Awp[id] = (f16)src[(m & 255) * KTOT + ch * 9 + s];
}

/* =====================================================================
 * Kernel 1b: input NCHW f32 -> zero-guard-padded pixel-major fp16
 * xp[b][130][130][64], 16B chunks XOR-permuted by (padded_col & 7).
 * ===================================================================== */
__global__ __launch_bounds__(256) void lte_prep_x(
    const float* __restrict__ inp, f16* __restrict__ xp) {
  int id = blockIdx.x * 256 + threadIdx.x;   /* padded row id, NB*16900 */
  if (id >= NB * XROWS) return;
  int b  = id / XROWS;
  int rr = id - b * XROWS;
  int yy = rr / XROW;
  int pc = rr - yy * XROW;      /* padded col 0..129 */
  int x  = pc - 1;
  int y  = yy - 1;
  f16* op = xp + (size_t)id * 64;
  if ((unsigned)y < 128u && (unsigned)x < 128u) {
    const float* ip = inp + (size_t)b * CIN * NPIX + y * WW + x;
    const int p7 = pc & 7;
#pragma unroll
    for (int q = 0; q < 8; ++q) {
      f16x8 v;
#pragma unroll
      for (int k = 0; k < 8; ++k) v[k] = (f16)ip[(((q ^ p7) << 3) + k) * NPIX];
      *(f16x8*)(op + q * 8) = v;
    }
  } else {
    f16x8 z = {};
#pragma unroll
    for (int q = 0; q < 8; ++q) *(f16x8*)(op + q * 8) = z;
  }
}

/* =====================================================================
 * Kernel 2: implicit-im2col GEMM (validated R10-R14). UNCHANGED.
 * ===================================================================== */
__global__ __launch_bounds__(256, 3) void lte_conv_gemm(
    const f16* __restrict__ xp, const f16* __restrict__ Awp,
    const float* __restrict__ coef_b, const float* __restrict__ freq_b,
    char* __restrict__ YT) {
  __shared__ f16 Bs[3 * 136 * 64];    /* 52,224 B; reused by epilogue */

  const int t  = threadIdx.x;
  const int bx = blockIdx.x;
  const int mt = blockIdx.y;
  const int bb = blockIdx.z;
  const int l  = t & 63;
  const int w  = t >> 6;
  const int wr = __builtin_amdgcn_readfirstlane(w >> 1);
  const int wc = __builtin_amdgcn_readfirstlane(w & 1);
  const int lm = l & 15;

  f32x4 acc[4][4] = {};

  const f16* xb = xp + (size_t)bb * XROWS * 64;
  const f16* Aw = Awp + (size_t)((mt * 2 + wr) * 9) * 4096 + l * 8;

  for (int c = w; c < 51; c += 4) {
    const int rr = c / 17, cc = c - rr * 17;
    gload16(xb + (size_t)((bx + rr) * XROW + cc * 8) * 64 + l * 8,
            Bs + (rr * 136 + cc * 8) * 64);
  }

  f16x8 afb[2][4];
#define LOAD_AF(buf_, h_)                                                    \
  {                                                                          \
    const f16* ap_ = Aw + ((h_) >> 1) * 4096 + ((h_) & 1) * 2048;            \
    afb[buf_][0] = *(const f16x8*)(ap_);                                     \
    afb[buf_][1] = *(const f16x8*)(ap_ + 512);                               \
    afb[buf_][2] = *(const f16x8*)(ap_ + 1024);                              \
    afb[buf_][3] = *(const f16x8*)(ap_ + 1536);                              \
  }

  LOAD_AF(0, 0)
  asm volatile("s_waitcnt vmcnt(0)" ::: "memory");
  __builtin_amdgcn_s_barrier();

#pragma unroll
  for (int h = 0; h < 18; ++h) {
    const int s  = h >> 1;
    const int ks = h & 1;
    if (h < 17) LOAD_AF((h + 1) & 1, h + 1)
    const int ky = s / 3, kx = s - 3 * (s / 3);
    const int jl = ks * 4 + (l >> 4);
    f16x8 bg[4];
#pragma unroll
    for (int ni = 0; ni < 4; ++ni) {
      const int xc = wc * 64 + ni * 16 + lm + kx;
      bg[ni] = *(const f16x8*)&Bs[(ky * 136 + xc) * 64 + ((jl ^ (xc & 7)) << 3)];
    }
#pragma unroll
    for (int mi = 0; mi < 4; ++mi)
#pragma unroll
      for (int ni = 0; ni < 4; ++ni)
        acc[mi][ni] = __builtin_amdgcn_mfma_f32_16x16x32_f16(afb[h & 1][mi], bg[ni], acc[mi][ni], 0, 0, 0);
  }

  __syncthreads();
  const float* bias = (mt < 2) ? (coef_b + mt * 128) : (freq_b + (mt - 2) * 128);
  const int rj = (l >> 4) * 4;
  if (mt < 2) {
    char* lt8 = (char*)Bs;               /* [128][144] */
#pragma unroll
    for (int mi = 0; mi < 4; ++mi) {
      const int bm = wr * 64 + mi * 16 + rj;
      const float b0 = bias[bm], b1 = bias[bm + 1], b2 = bias[bm + 2], b3 = bias[bm + 3];
#pragma unroll
      for (int ni = 0; ni < 4; ++ni) {
        const int p = wc * 64 + ni * 16 + lm;
        f32x4 v = acc[mi][ni];
        *(unsigned*)&lt8[p * 144 + bm] = pack8(v[0] + b0, v[1] + b1, v[2] + b2, v[3] + b3);
      }
    }
    __syncthreads();
    char* yb8 = YT + (size_t)(bb * NPIX + bx * 128) * RECB + mt * 128;
#pragma unroll
    for (int it = 0; it < 4; ++it) {
      const int p = it * 32 + (t >> 3);
      const int off = (t & 7) * 16;
      uint4 v = *(const uint4*)&lt8[p * 144 + off];
      *(uint4*)&yb8[(size_t)p * RECB + off] = v;
    }
  } else {
    short* lt = (short*)Bs;              /* [128][138] */
#pragma unroll
    for (int mi = 0; mi < 4; ++mi) {
      const int bm = wr * 64 + mi * 16 + rj;
      const float b0 = bias[bm], b1 = bias[bm + 1], b2 = bias[bm + 2], b3 = bias[bm + 3];
#pragma unroll
      for (int ni = 0; ni < 4; ++ni) {
        const int p = wc * 64 + ni * 16 + lm;
        f32x4 v = acc[mi][ni];
        uint2 q2; q2.x = packq(v[0] + b0, v[1] + b1); q2.y = packq(v[2] + b2, v[3] + b3);
        *(uint2*)&lt[p * 138 + bm] = q2;
      }
    }
    __syncthreads();
    short* yb = (short*)(YT + (size_t)(bb * NPIX + bx * 128) * RECB + 256) + (mt - 2) * 128;
    const int lp = l >> 5;
    const int c4 = (l & 31) * 4;
#pragma unroll
    for (int it = 0; it < 16; ++it) {
      const int p = it * 8 + w * 2 + lp;
      uint2 v = *(const uint2*)&lt[p * 138 + c4];
      *(uint2*)&yb[(size_t)p * (RECB / 2) + c4] = v;
    }
  }
}

/* =====================================================================
 * Kernel 3: 4-corner nearest sample + sin/cos modulation.
 * R14 quad-register structure (validated, 62us) + NEW: 256 threads/blk,
 * two query-halves (qh = tid>>7 owns 8 queries as 2 quads) — serial
 * latency rounds per thread 4 -> 2, waves/block 2 -> 4. Phase A/B/C
 * code identical per-thread; only lout column mapping + final transpose
 * re-derived for 256 threads. Index path bit-exact — unchanged math.
 * ===================================================================== */
__global__ __launch_bounds__(256) void lte_sample(
    const char* __restrict__ YT, const float* __restrict__ coord,
    const float* __restrict__ cell, const float* __restrict__ phase_w,
    float* __restrict__ out) {
  __shared__ float lout[256 * 17];
  const int tid   = threadIdx.x;          /* 0..255 */
  const int j     = tid & 127;            /* channel lane */
  const int qh    = tid >> 7;             /* query half: 0 or 1 */
  const int q0    = blockIdx.x * 16;      /* global over B*Q */
  const int b     = q0 >> 14;
  const int q0loc = q0 & (NPIX - 1);
  const float pw0 = phase_w[2 * j], pw1 = phase_w[2 * j + 1];
  const char* Yb = YT + (size_t)b * NPIX * RECB;

  for (int qq = 0; qq < 2; ++qq) {        /* 2 quads of 4 queries per half */
    float ph[4], tot[4], a3[4];
    float rel0[4][4], rel1[4][4];
    int   off[4][4];
    /* ---- phase A: index math (bit-exact path), no memory ---- */
#pragma unroll
    for (int qi = 0; qi < 4; ++qi) {
      const int qg = q0 + qh * 8 + qq * 4 + qi;
      const float c0  = coord[2 * qg], c1 = coord[2 * qg + 1];
      const float ce0 = cell[2 * qg],  ce1 = cell[2 * qg + 1];
      ph[qi]  = (ce0 * 128.0f) * pw0 + (ce1 * 128.0f) * pw1;
      tot[qi] = 0.f;
#pragma unroll
      for (int ci = 0; ci < 4; ++ci) {   /* (vx,vy): (-,-),(-,+),(+,-),(+,+) */
        const float s0 = (ci & 2) ? SHP : SHM;
        const float s1 = (ci & 1) ? SHP : SHM;
        float cx = fminf(fmaxf(c0 + s0, CLO), CHI);
        float cy = fminf(fmaxf(c1 + s1, CLO), CHI);
        float ty = ((cx + 1.0f) * 128.0f - 1.0f) * 0.5f;
        float tx = ((cy + 1.0f) * 128.0f - 1.0f) * 0.5f;
        float fy = fminf(fmaxf(rintf(ty), 0.f), 127.f); /* round half-even */
        float fx = fminf(fmaxf(rintf(tx), 0.f), 127.f);
        int iy = (int)fy, ix = (int)fx;
        float qcy = -1.0f + (2.0f * fy + 1.0f) * (1.0f / 128.0f);
        float qcx = -1.0f + (2.0f * fx + 1.0f) * (1.0f / 128.0f);
        rel0[qi][ci] = (c0 - qcy) * 128.0f;
        rel1[qi][ci] = (c1 - qcx) * 128.0f;
        float ar = fabsf(rel0[qi][ci] * rel1[qi][ci]);
        tot[qi] += ar + 1e-9f;
        if (ci == 3) a3[qi] = ar;
        off[qi][ci] = (iy * 128 + ix) * RECB;
      }
    }
    /* ---- phase B: issue all 48 gathers (static arrays) ---- */
    int rA[4][4], rB[4][4], rU[4][4];
#pragma unroll
    for (int qi = 0; qi < 4; ++qi)
#pragma unroll
      for (int ci = 0; ci < 4; ++ci) {
        const char* bp = Yb + off[qi][ci];
        rA[qi][ci] = (int)*(const signed char*)(bp + j);
        rB[qi][ci] = (int)*(const signed char*)(bp + 128 + j);
        rU[qi][ci] = *(const int*)(bp + 256 + 4 * j);
      }
    /* ---- phase C: trig + accumulate + LDS stage ---- */
#pragma unroll
    for (int qi = 0; qi < 4; ++qi) {
      float accC = 0.f, accS = 0.f;
#pragma unroll
      for (int ci = 0; ci < 4; ++ci) {
        float coefA = (float)rA[qi][ci] * Q8ISCL;
        float coefB = (float)rB[qi][ci] * Q8ISCL;
        int u = rU[qi][ci];
        float f0 = (float)((short)(u & 0xFFFF)) * QISCL;
        float f1 = (float)((short)(u >> 16)) * QISCL;
        float f = f0 * rel0[qi][ci] + f1 * rel1[qi][ci] + ph[qi];
        float ang = PIF * f;
        accC += coefA * __cosf(ang);
        accS += coefB * __sinf(ang);
      }
      const float wgt = a3[qi] / tot[qi];
      const int col = qh * 8 + qq * 4 + qi;
      lout[j * 17 + col]         = accC * wgt;
      lout[(j + 128) * 17 + col] = accS * wgt;
    }
  }
  __syncthreads();
  /* final transpose: 256 threads x 4 passes x float4 = 256ch x 16q */
#pragma unroll
  for (int pass = 0; pass < 4; ++pass) {
    int c  = pass * 64 + (tid >> 2);
    int qf = (tid & 3) * 4;
    float4 v;
    v.x = lout[c * 17 + qf];     v.y = lout[c * 17 + qf + 1];
    v.z = lout[c * 17 + qf + 2]; v.w = lout[c * 17 + qf + 3];
    *(float4*)(out + (((size_t)(b * 256 + c)) << 14) + q0loc + qf) = v;
  }
}

extern "C" void kernel_launch(void* const* d_in, const int* in_sizes, int n_in,
                              void* d_out, int out_size, void* d_ws, size_t ws_size,
                              hipStream_t stream) {
  const float* inp     = (const float*)d_in[0];
  const float* coord   = (const float*)d_in[1];
  const float* cell    = (const float*)d_in[2];
  const float* coef_w  = (const float*)d_in[3];
  const float* coef_b  = (const float*)d_in[4];
  const float* freq_w  = (const float*)d_in[5];
  const float* freq_b  = (const float*)d_in[6];
  const float* phase_w = (const float*)d_in[7];
  float* out = (float*)d_out;

  /* ws: Awp fp16 (0.59MB) | xp_pad fp16 (8.65MB + slack) | YT 768B-rec (50.3MB) */
  f16* Awp = (f16*)d_ws;
  f16* xp  = (f16*)((char*)d_ws + (size_t)WELEM * 2);
  char* YT = (char*)d_ws + (size_t)WELEM * 2 + ((size_t)NB * XROWS + 8) * 64 * 2;

  lte_prep_w<<<dim3(1152), dim3(256), 0, stream>>>(coef_w, freq_w, Awp);
  lte_prep_x<<<dim3((NB * XROWS + 255) / 256), dim3(256), 0, stream>>>(inp, xp);
  lte_conv_gemm<<<dim3(128, 4, 4), dim3(256), 0, stream>>>(xp, Awp, coef_b, freq_b, YT);
  lte_sample<<<dim3(4096), dim3(256), 0, stream>>>(YT, coord, cell, phase_w, out);
}

// Round 18
// 116.333 us; speedup vs baseline: 1.8409x; 1.0219x over previous
//
#include <hip/hip_runtime.h>

typedef unsigned short u16;
typedef _Float16 f16;

#define CIN   64
#define HH    128
#define WW    128
#define NPIX  16384   /* HH*WW */
#define HID   256
#define MTOT  512     /* coef(256) + freq(256) stacked */
#define KTOT  576     /* 64 ch * 9 taps */
#define NB    4
#define WELEM 294912  /* MTOT*KTOT */
#define XROW  130     /* padded input grid row */
#define XROWS 16900   /* 130*130 rows per batch */
#define RECB  768     /* YT record: 256 int8 coef + 256 int16 freq */

/* index-path constants: must bit-match the f32 trace of the reference */
#define SHM  ((float)(-0.0078125 + 1e-6))
#define SHP  ((float)( 0.0078125 + 1e-6))
#define CLO  ((float)(-1.0 + 1e-6))
#define CHI  ((float)( 1.0 - 1e-6))
#define PIF  3.14159265358979323846f

#define QSCL   1024.0f         /* int16 fixed-point scale (freq) */
#define QISCL  (1.0f / 1024.0f)
#define Q8SCL  16.0f           /* int8 fixed-point scale (coef)  */
#define Q8ISCL 0.0625f

using f32x4 = __attribute__((ext_vector_type(4))) float;
using f16x8 = __attribute__((ext_vector_type(8))) _Float16;

/* ---- async global->LDS DMA (dest = wave base + lane*16) ---- */
typedef __attribute__((address_space(1))) const void gas_void;
typedef __attribute__((address_space(3))) void las_void;
__device__ __forceinline__ void gload16(const void* g, void* l) {
  __builtin_amdgcn_global_load_lds((gas_void*)g, (las_void*)l, 16, 0, 0);
}

__device__ __forceinline__ unsigned packq(float a, float b) {  /* int16 x2 */
  float fa = fminf(fmaxf(a * QSCL, -32767.f), 32767.f);
  float fb = fminf(fmaxf(b * QSCL, -32767.f), 32767.f);
  int ia = (int)rintf(fa), ib = (int)rintf(fb);
  return ((unsigned)(unsigned short)(short)ia) | (((unsigned)(unsigned short)(short)ib) << 16);
}
__device__ __forceinline__ unsigned pack8(float a, float b, float c, float d) { /* int8 x4 */
  int ia = (int)rintf(fminf(fmaxf(a * Q8SCL, -127.f), 127.f));
  int ib = (int)rintf(fminf(fmaxf(b * Q8SCL, -127.f), 127.f));
  int ic = (int)rintf(fminf(fmaxf(c * Q8SCL, -127.f), 127.f));
  int id = (int)rintf(fminf(fmaxf(d * Q8SCL, -127.f), 127.f));
  return (ia & 255) | ((ib & 255) << 8) | ((ic & 255) << 16) | ((id & 255) << 24);
}

/* =====================================================================
 * Kernel 1: repack conv weights -> fp16 for DIRECT global->register
 * fragment loads (layout validated R10-R17, unchanged).
 * ===================================================================== */
__global__ __launch_bounds__(256) void lte_prep_w(
    const float* __restrict__ cw, const float* __restrict__ fw,
    f16* __restrict__ Awp) {
  int id = blockIdx.x * 256 + threadIdx.x;
  if (id >= WELEM) return;
  int e  = id & 7;
  int l  = (id >> 3) & 63;
  int mi = (id >> 9) & 3;
  int r  = id >> 11;
  int ks = r & 1;
  int r2 = r >> 1;
  int s  = r2 % 9;
  int q  = r2 / 9;
  int wr = q & 1;
  int mt = q >> 1;
  int m  = mt * 128 + wr * 64 + mi * 16 + (l & 15);
  int ch = (ks * 4 + (l >> 4)) * 8 + e;
  const float* src = (m < HID) ? cw : fw;
  Awp[id] = (f16)src[(m & 255) * KTOT + ch * 9 + s];
}

/* =====================================================================
 * Kernel 1b: input NCHW f32 -> zero-guard-padded pixel-major fp16
 * xp[b][130][130][64], 16B chunks XOR-permuted by (padded_col & 7).
 * Unchanged (validated).
 * ===================================================================== */
__global__ __launch_bounds__(256) void lte_prep_x(
    const float* __restrict__ inp, f16* __restrict__ xp) {
  int id = blockIdx.x * 256 + threadIdx.x;   /* padded row id, NB*16900 */
  if (id >= NB * XROWS) return;
  int b  = id / XROWS;
  int rr = id - b * XROWS;
  int yy = rr / XROW;
  int pc = rr - yy * XROW;      /* padded col 0..129 */
  int x  = pc - 1;
  int y  = yy - 1;
  f16* op = xp + (size_t)id * 64;
  if ((unsigned)y < 128u && (unsigned)x < 128u) {
    const float* ip = inp + (size_t)b * CIN * NPIX + y * WW + x;
    const int p7 = pc & 7;
#pragma unroll
    for (int q = 0; q < 8; ++q) {
      f16x8 v;
#pragma unroll
      for (int k = 0; k < 8; ++k) v[k] = (f16)ip[(((q ^ p7) << 3) + k) * NPIX];
      *(f16x8*)(op + q * 8) = v;
    }
  } else {
    f16x8 z = {};
#pragma unroll
    for (int q = 0; q < 8; ++q) *(f16x8*)(op + q * 8) = z;
  }
}

/* =====================================================================
 * Kernel 2: implicit-im2col GEMM, REBALANCED (R17 diagnosis: A-stream
 * L2-BW-bound at 256B/MFMA). Block 128(M)x256(N) (2 image rows), 4
 * waves, wave tile 64x128 (mi=4, ni=8): A-bytes/MFMA 256->128, B-LDS
 * becomes the wall (~40% predicted MfmaUtil). B staged ONCE as a LINEAR
 * 520-px copy of xp rows 2bx..2bx+3 (halos automatic via xp 130-pitch).
 * Barrier-free K-loop + A reg-dbuf (validated). wc-pair waves share af
 * streams (L1 dedup). Epilogue LDS-transpose for 256-px tiles.
 * ===================================================================== */
__global__ __launch_bounds__(256, 2) void lte_conv_gemm(
    const f16* __restrict__ xp, const f16* __restrict__ Awp,
    const float* __restrict__ coef_b, const float* __restrict__ freq_b,
    char* __restrict__ YT) {
  /* staging 520*128B = 66,560; epilogue int16 [256][138]*2 = 70,656 */
  __shared__ __attribute__((aligned(16))) char Bsm[70656];
  f16* Bs = (f16*)Bsm;

  const int t  = threadIdx.x;
  const int bx = blockIdx.x;     /* pixel tile [bx*256,+256) = rows 2bx,2bx+1 */
  const int mt = blockIdx.y;     /* m tile (0..3) */
  const int bb = blockIdx.z;     /* batch */
  const int l  = t & 63;
  const int w  = t >> 6;         /* 0..3 */
  const int wr = __builtin_amdgcn_readfirstlane(w >> 1);  /* M half 0/1 */
  const int wc = __builtin_amdgcn_readfirstlane(w & 1);   /* N half = row parity */
  const int lm = l & 15;

  f32x4 acc[4][8] = {};

  const f16* xb = xp + (size_t)bb * XROWS * 64;
  const f16* Aw = Awp + (size_t)((mt * 2 + wr) * 9) * 4096 + l * 8;

  /* ---- prologue: linear DMA copy of xp padded rows 2bx..2bx+3
     (520 px x 128B = 66,560B, 65 x 1KB calls) ---- */
  {
    const f16* src = xb + (size_t)(2 * bx) * XROW * 64;
    for (int c = w; c < 65; c += 4)
      gload16(src + c * 512 + l * 8, Bs + c * 512);
  }

  f16x8 afb[2][4];                     /* named dbuf; h&1 static after unroll */
#define LOAD_AF(buf_, h_)                                                    \
  {                                                                          \
    const f16* ap_ = Aw + ((h_) >> 1) * 4096 + ((h_) & 1) * 2048;            \
    afb[buf_][0] = *(const f16x8*)(ap_);                                     \
    afb[buf_][1] = *(const f16x8*)(ap_ + 512);                               \
    afb[buf_][2] = *(const f16x8*)(ap_ + 1024);                              \
    afb[buf_][3] = *(const f16x8*)(ap_ + 1536);                              \
  }

  LOAD_AF(0, 0)
  asm volatile("s_waitcnt vmcnt(0)" ::: "memory");
  __builtin_amdgcn_s_barrier();

#pragma unroll
  for (int h = 0; h < 18; ++h) {
    const int s  = h >> 1;
    const int ks = h & 1;
    if (h < 17) LOAD_AF((h + 1) & 1, h + 1)          /* issue-early */
    const int ky = s / 3, kx = s - 3 * (s / 3);
    const int jl = ks * 4 + (l >> 4);
    f16x8 bg[8];
#pragma unroll
    for (int ni = 0; ni < 8; ++ni) {
      const int xc = ni * 16 + lm + kx;              /* 0..129 */
      bg[ni] = *(const f16x8*)&Bs[((wc + ky) * 130 + xc) * 64 + ((jl ^ (xc & 7)) << 3)];
    }
#pragma unroll
    for (int mi = 0; mi < 4; ++mi)
#pragma unroll
      for (int ni = 0; ni < 8; ++ni)
        acc[mi][ni] = __builtin_amdgcn_mfma_f32_16x16x32_f16(afb[h & 1][mi], bg[ni], acc[mi][ni], 0, 0, 0);
  }

  /* ---- epilogue: +bias, quantize -> LDS transpose -> coalesced stores.
     mt<2: int8 [256][144]; mt>=2: int16 [256][138]. ---- */
  __syncthreads();                       /* all waves done reading Bs */
  const float* bias = (mt < 2) ? (coef_b + mt * 128) : (freq_b + (mt - 2) * 128);
  const int rj = (l >> 4) * 4;
  if (mt < 2) {
    char* lt8 = Bsm;                     /* [256][144] = 36,864B */
#pragma unroll
    for (int mi = 0; mi < 4; ++mi) {
      const int bm = wr * 64 + mi * 16 + rj;    /* channel 0..127 */
      const float b0 = bias[bm], b1 = bias[bm + 1], b2 = bias[bm + 2], b3 = bias[bm + 3];
#pragma unroll
      for (int ni = 0; ni < 8; ++ni) {
        const int p = wc * 128 + ni * 16 + lm;  /* block-local pixel 0..255 */
        f32x4 v = acc[mi][ni];
        *(unsigned*)&lt8[p * 144 + bm] = pack8(v[0] + b0, v[1] + b1, v[2] + b2, v[3] + b3);
      }
    }
    __syncthreads();
    char* yb8 = YT + (size_t)(bb * NPIX + bx * 256) * RECB + mt * 128;
#pragma unroll
    for (int it = 0; it < 8; ++it) {
      const int p = it * 32 + (t >> 3);
      const int off = (t & 7) * 16;
      uint4 v = *(const uint4*)&lt8[p * 144 + off];
      *(uint4*)&yb8[(size_t)p * RECB + off] = v;
    }
  } else {
    short* lt = (short*)Bsm;             /* [256][138] = 70,656B */
#pragma unroll
    for (int mi = 0; mi < 4; ++mi) {
      const int bm = wr * 64 + mi * 16 + rj;
      const float b0 = bias[bm], b1 = bias[bm + 1], b2 = bias[bm + 2], b3 = bias[bm + 3];
#pragma unroll
      for (int ni = 0; ni < 8; ++ni) {
        const int p = wc * 128 + ni * 16 + lm;
        f32x4 v = acc[mi][ni];
        uint2 q2; q2.x = packq(v[0] + b0, v[1] + b1); q2.y = packq(v[2] + b2, v[3] + b3);
        *(uint2*)&lt[p * 138 + bm] = q2;
      }
    }
    __syncthreads();
    short* yb = (short*)(YT + (size_t)(bb * NPIX + bx * 256) * RECB + 256) + (mt - 2) * 128;
    const int lp = l >> 5;
    const int c4 = (l & 31) * 4;
#pragma unroll
    for (int it = 0; it < 32; ++it) {
      const int p = it * 8 + w * 2 + lp;
      uint2 v = *(const uint2*)&lt[p * 138 + c4];
      *(uint2*)&yb[(size_t)p * (RECB / 2) + c4] = v;
    }
  }
}

/* =====================================================================
 * Kernel 3: 4-corner nearest sample + sin/cos modulation.
 * R17 structure (validated): 256 thr, 2 query-halves x 2 quads.
 * Index path bit-exact — unchanged.
 * ===================================================================== */
__global__ __launch_bounds__(256) void lte_sample(
    const char* __restrict__ YT, const float* __restrict__ coord,
    const float* __restrict__ cell, const float* __restrict__ phase_w,
    float* __restrict__ out) {
  __shared__ float lout[256 * 17];
  const int tid   = threadIdx.x;          /* 0..255 */
  const int j     = tid & 127;            /* channel lane */
  const int qh    = tid >> 7;             /* query half: 0 or 1 */
  const int q0    = blockIdx.x * 16;      /* global over B*Q */
  const int b     = q0 >> 14;
  const int q0loc = q0 & (NPIX - 1);
  const float pw0 = phase_w[2 * j], pw1 = phase_w[2 * j + 1];
  const char* Yb = YT + (size_t)b * NPIX * RECB;

  for (int qq = 0; qq < 2; ++qq) {        /* 2 quads of 4 queries per half */
    float ph[4], tot[4], a3[4];
    float rel0[4][4], rel1[4][4];
    int   off[4][4];
#pragma unroll
    for (int qi = 0; qi < 4; ++qi) {
      const int qg = q0 + qh * 8 + qq * 4 + qi;
      const float c0  = coord[2 * qg], c1 = coord[2 * qg + 1];
      const float ce0 = cell[2 * qg],  ce1 = cell[2 * qg + 1];
      ph[qi]  = (ce0 * 128.0f) * pw0 + (ce1 * 128.0f) * pw1;
      tot[qi] = 0.f;
#pragma unroll
      for (int ci = 0; ci < 4; ++ci) {   /* (vx,vy): (-,-),(-,+),(+,-),(+,+) */
        const float s0 = (ci & 2) ? SHP : SHM;
        const float s1 = (ci & 1) ? SHP : SHM;
        float cx = fminf(fmaxf(c0 + s0, CLO), CHI);
        float cy = fminf(fmaxf(c1 + s1, CLO), CHI);
        float ty = ((cx + 1.0f) * 128.0f - 1.0f) * 0.5f;
        float tx = ((cy + 1.0f) * 128.0f - 1.0f) * 0.5f;
        float fy = fminf(fmaxf(rintf(ty), 0.f), 127.f); /* round half-even */
        float fx = fminf(fmaxf(rintf(tx), 0.f), 127.f);
        int iy = (int)fy, ix = (int)fx;
        float qcy = -1.0f + (2.0f * fy + 1.0f) * (1.0f / 128.0f);
        float qcx = -1.0f + (2.0f * fx + 1.0f) * (1.0f / 128.0f);
        rel0[qi][ci] = (c0 - qcy) * 128.0f;
        rel1[qi][ci] = (c1 - qcx) * 128.0f;
        float ar = fabsf(rel0[qi][ci] * rel1[qi][ci]);
        tot[qi] += ar + 1e-9f;
        if (ci == 3) a3[qi] = ar;
        off[qi][ci] = (iy * 128 + ix) * RECB;
      }
    }
    int rA[4][4], rB[4][4], rU[4][4];
#pragma unroll
    for (int qi = 0; qi < 4; ++qi)
#pragma unroll
      for (int ci = 0; ci < 4; ++ci) {
        const char* bp = Yb + off[qi][ci];
        rA[qi][ci] = (int)*(const signed char*)(bp + j);
        rB[qi][ci] = (int)*(const signed char*)(bp + 128 + j);
        rU[qi][ci] = *(const int*)(bp + 256 + 4 * j);
      }
#pragma unroll
    for (int qi = 0; qi < 4; ++qi) {
      float accC = 0.f, accS = 0.f;
#pragma unroll
      for (int ci = 0; ci < 4; ++ci) {
        float coefA = (float)rA[qi][ci] * Q8ISCL;
        float coefB = (float)rB[qi][ci] * Q8ISCL;
        int u = rU[qi][ci];
        float f0 = (float)((short)(u & 0xFFFF)) * QISCL;
        float f1 = (float)((short)(u >> 16)) * QISCL;
        float f = f0 * rel0[qi][ci] + f1 * rel1[qi][ci] + ph[qi];
        float ang = PIF * f;
        accC += coefA * __cosf(ang);
        accS += coefB * __sinf(ang);
      }
      const float wgt = a3[qi] / tot[qi];
      const int col = qh * 8 + qq * 4 + qi;
      lout[j * 17 + col]         = accC * wgt;
      lout[(j + 128) * 17 + col] = accS * wgt;
    }
  }
  __syncthreads();
#pragma unroll
  for (int pass = 0; pass < 4; ++pass) {
    int c  = pass * 64 + (tid >> 2);
    int qf = (tid & 3) * 4;
    float4 v;
    v.x = lout[c * 17 + qf];     v.y = lout[c * 17 + qf + 1];
    v.z = lout[c * 17 + qf + 2]; v.w = lout[c * 17 + qf + 3];
    *(float4*)(out + (((size_t)(b * 256 + c)) << 14) + q0loc + qf) = v;
  }
}

extern "C" void kernel_launch(void* const* d_in, const int* in_sizes, int n_in,
                              void* d_out, int out_size, void* d_ws, size_t ws_size,
                              hipStream_t stream) {
  const float* inp     = (const float*)d_in[0];
  const float* coord   = (const float*)d_in[1];
  const float* cell    = (const float*)d_in[2];
  const float* coef_w  = (const float*)d_in[3];
  const float* coef_b  = (const float*)d_in[4];
  const float* freq_w  = (const float*)d_in[5];
  const float* freq_b  = (const float*)d_in[6];
  const float* phase_w = (const float*)d_in[7];
  float* out = (float*)d_out;

  /* ws: Awp fp16 (0.59MB) | xp_pad fp16 (8.65MB + slack) | YT 768B-rec (50.3MB) */
  f16* Awp = (f16*)d_ws;
  f16* xp  = (f16*)((char*)d_ws + (size_t)WELEM * 2);
  char* YT = (char*)d_ws + (size_t)WELEM * 2 + ((size_t)NB * XROWS + 8) * 64 * 2;

  lte_prep_w<<<dim3(1152), dim3(256), 0, stream>>>(coef_w, freq_w, Awp);
  lte_prep_x<<<dim3((NB * XROWS + 255) / 256), dim3(256), 0, stream>>>(inp, xp);
  lte_conv_gemm<<<dim3(64, 4, 4), dim3(256), 0, stream>>>(xp, Awp, coef_b, freq_b, YT);
  lte_sample<<<dim3(4096), dim3(256), 0, stream>>>(YT, coord, cell, phase_w, out);
}